// Round 19
// baseline (1063.467 us; speedup 1.0000x reference)
//
#include <hip/hip_runtime.h>
#include <math.h>

typedef unsigned char  u8;
typedef unsigned short u16;
typedef unsigned int   u32;
typedef __attribute__((ext_vector_type(8))) short bf16x8;
typedef __attribute__((ext_vector_type(8))) int   i32x8;
typedef __attribute__((ext_vector_type(4))) float f32x4;

typedef const void __attribute__((address_space(1))) gv1_t;
typedef void       __attribute__((address_space(3))) lv3_t;
#define GLL(g, l) __builtin_amdgcn_global_load_lds((gv1_t*)(g), (lv3_t*)(l), 16, 0, 0)

__device__ __forceinline__ u16 f2b(float x) {
    union { float f; u32 u; } v; v.f = x;
    u32 r = v.u + 0x7FFFu + ((v.u >> 16) & 1u);
    return (u16)(r >> 16);
}
__device__ __forceinline__ float b2f(u32 x) {
    union { u32 u; float f; } v; v.u = x << 16;
    return v.f;
}
__device__ __forceinline__ float fast_sigmoid(float x) {
    return __builtin_amdgcn_rcpf(1.0f + __builtin_amdgcn_exp2f(-x * 1.44269504f));
}
__device__ __forceinline__ float fast_tanh(float x) {
    return 2.0f * __builtin_amdgcn_rcpf(1.0f + __builtin_amdgcn_exp2f(-x * 2.88539008f)) - 1.0f;
}

// f32 -> OCP e4m3fn (RNE-ish, clamp 448, subnormals via *512 round)
__device__ __forceinline__ u8 f2e4m3(float x) {
    union { float f; u32 u; } v; v.f = x;
    u32 s = (v.u >> 24) & 0x80u;
    u32 a = v.u & 0x7fffffffu;
    if (a >= 0x43d80000u) return (u8)(s | 0x7e);
    if (a >= 0x3c800000u) {
        u32 expf = a >> 23;
        u32 keep = (a >> 20) & 7u;
        u32 rest = a & 0xfffffu;
        u32 vv = ((expf - 120u) << 3) | keep;
        vv += (rest > 0x80000u) || ((rest == 0x80000u) && (keep & 1u));
        return (u8)(s | vv);
    }
    float t = fabsf(x) * 512.0f;
    u32 ti = (u32)(t + 0.5f);
    return (u8)(s | ti);
}
__device__ __forceinline__ float e4m3f(u32 b) {
    u32 e = (b >> 3) & 15u, m = b & 7u;
    union { u32 u; float f; } t;
    t.u = ((e + 120u) << 23) | (m << 20);
    float v = e ? t.f : ((float)m * 0.001953125f);
    return (b & 0x80u) ? -v : v;
}

// ===========================================================================
// SWZ128 storage for fp8 GEMM operands: within each 128B-aligned row segment,
// 16B chunk c stored at phys c ^ (row&7). GLL staging is a pure linear copy;
// fragment reads apply the XOR.
// ===========================================================================

// prep: adj f32 -> fp8 (x8192), swz128 store
__global__ void cvt_adj_fp8(const float* __restrict__ a, u8* __restrict__ o, int n) {
    for (int i = (blockIdx.x * 256 + threadIdx.x) * 4; i < n; i += gridDim.x * 256 * 4) {
        float4 v = *(const float4*)&a[i];
        u32 pk = (u32)f2e4m3(v.x * 8192.0f) | ((u32)f2e4m3(v.y * 8192.0f) << 8)
               | ((u32)f2e4m3(v.z * 8192.0f) << 16) | ((u32)f2e4m3(v.w * 8192.0f) << 24);
        int row = i >> 12;                       // 4096 B per row
        int addr = (i & ~127) | (((((i >> 4) & 7) ^ (row & 7)) << 4)) | (i & 15);
        *(u32*)&o[addr] = pk;
    }
}

// prep: x = data + temb + semb; Xn bf16 [b][t][n][c]; XT fp8 swz128
__global__ void prep_x(const float* __restrict__ data, const float* __restrict__ temb,
                       const float* __restrict__ semb, u16* __restrict__ Xn, u8* __restrict__ XT) {
    const int n0 = blockIdx.x * 64, t = blockIdx.y, b = blockIdx.z;
    const int tid = threadIdx.x;
    __shared__ u16 lt[64][66];
#pragma unroll
    for (int p = 0; p < 4; p++) {
        int n = p * 16 + (tid >> 4);
        int c = (tid & 15) * 4;
        size_t gi = ((size_t)(b * 12 + t) * 1024 + n0 + n) * 64 + c;
        float4 v  = *(const float4*)&data[gi];
        float4 tv = *(const float4*)&temb[t * 64 + c];
        float4 sv = *(const float4*)&semb[(n0 + n) * 64 + c];
        u16 u0 = f2b(v.x + tv.x + sv.x);
        u16 u1 = f2b(v.y + tv.y + sv.y);
        u16 u2 = f2b(v.z + tv.z + sv.z);
        u16 u3 = f2b(v.w + tv.w + sv.w);
        uint2 pk; pk.x = (u32)u0 | ((u32)u1 << 16); pk.y = (u32)u2 | ((u32)u3 << 16);
        *(uint2*)&Xn[gi] = pk;
        lt[n][c + 0] = u0; lt[n][c + 1] = u1; lt[n][c + 2] = u2; lt[n][c + 3] = u3;
    }
    __syncthreads();
    const int c = tid >> 2, q = tid & 3;
    u32 w[4];
#pragma unroll
    for (int i = 0; i < 4; i++) {
        u32 b0 = f2e4m3(b2f(lt[q * 16 + i * 4 + 0][c]));
        u32 b1 = f2e4m3(b2f(lt[q * 16 + i * 4 + 1][c]));
        u32 b2 = f2e4m3(b2f(lt[q * 16 + i * 4 + 2][c]));
        u32 b3 = f2e4m3(b2f(lt[q * 16 + i * 4 + 3][c]));
        w[i] = b0 | (b1 << 8) | (b2 << 16) | (b3 << 24);
    }
    const int row = b * 64 + c;
    size_t kk = (size_t)t * 1024 + n0 + q * 16;
    size_t seg = kk & ~(size_t)127;
    int chunk = (((int)(kk >> 4) & 7) ^ (row & 7));
    uint4 pk; pk.x = w[0]; pk.y = w[1]; pk.z = w[2]; pk.w = w[3];
    *(uint4*)&XT[(size_t)row * 12288 + seg + chunk * 16] = pk;
}

// prep: fc_w -> Wt [27][128][64] bf16 ; conv weights -> Wc [128][128] bf16
__global__ void prep_w(const float* __restrict__ fcw, const float* __restrict__ cwl,
                       const float* __restrict__ cwr, u16* __restrict__ Wt, u16* __restrict__ Wc) {
    const int blk = blockIdx.x, tid = threadIdx.x;
    if (blk < 27) {
        const float* src = fcw + (size_t)blk * 64 * 128;
        u16* dst = Wt + (size_t)blk * 128 * 64;
        for (int e = tid; e < 8192; e += 256) {
            int c = e >> 7, f = e & 127;
            dst[f * 64 + c] = f2b(src[c * 128 + f]);
        }
    } else {
        for (int e = tid; e < 16384; e += 256) {
            int o = e >> 7, k = e & 127;
            float v = (o < 64) ? cwl[(o * 64 + (k & 63)) * 2 + (k >> 6)]
                               : cwr[((o - 64) * 64 + (k & 63)) * 2 + (k >> 6)];
            Wc[o * 128 + k] = f2b(v);
        }
    }
}

// ---------------------------------------------------------------------------
// gated dilated conv as GEMM (bf16, unchanged)
// ---------------------------------------------------------------------------
__global__ __launch_bounds__(256) void dconv_gemm(
    const u16* __restrict__ Xn, const u16* __restrict__ Wc,
    const float* __restrict__ cbl, const float* __restrict__ cbr,
    float* __restrict__ out) {
    const int n0 = blockIdx.x * 128, t = blockIdx.y, b = blockIdx.z;
    const int tid = threadIdx.x, lane = tid & 63, wid = tid >> 6;
    __shared__ u16 alds[2][128 * 32];
    const u16* base0 = Xn + (size_t)(b * 12 + t) * 1024 * 64;
    const u16* base3 = Xn + (size_t)(b * 12 + t + 3) * 1024 * 64;

    auto stage = [&](int buf, int kt) {
        int k0 = kt * 32;
#pragma unroll
        for (int q = 0; q < 2; q++) {
            int r = wid * 32 + q * 16 + (lane >> 2);
            int k = k0 + (lane & 3) * 8;
            const u16* gs = (k < 64) ? base0 + (size_t)(n0 + r) * 64 + k
                                     : base3 + (size_t)(n0 + r) * 64 + (k - 64);
            GLL(gs, &alds[buf][(wid * 32 + q * 16) * 32]);
        }
    };

    f32x4 acc[2][8] = {};
    stage(0, 0);
    __syncthreads();
    const int a_off = (wid * 32 + (lane & 15)) * 32 + (lane >> 4) * 8;
    for (int kt = 0; kt < 4; kt++) {
        int cur = kt & 1;
        if (kt < 3) stage(cur ^ 1, kt + 1);
        bf16x8 af[2];
#pragma unroll
        for (int m = 0; m < 2; m++) af[m] = *(const bf16x8*)&alds[cur][a_off + m * 16 * 32];
#pragma unroll
        for (int n = 0; n < 8; n++) {
            bf16x8 bq = *(const bf16x8*)&Wc[(n * 16 + (lane & 15)) * 128 + kt * 32 + (lane >> 4) * 8];
#pragma unroll
            for (int m = 0; m < 2; m++)
                acc[m][n] = __builtin_amdgcn_mfma_f32_16x16x32_bf16(af[m], bq, acc[m][n], 0, 0, 0);
        }
        __syncthreads();
    }
#pragma unroll
    for (int m = 0; m < 2; m++) {
#pragma unroll
        for (int n = 0; n < 4; n++) {
            int fp = n * 16 + (lane & 15);
            float b1 = cbl[fp], b2 = cbr[fp];
#pragma unroll
            for (int j = 0; j < 4; j++) {
                int row = wid * 32 + m * 16 + (lane >> 4) * 4 + j;
                float gl = acc[m][n][j] + b1;
                float gr = acc[m][n + 4][j] + b2;
                out[((size_t)(b * 9 + t) * 1024 + n0 + row) * 64 + fp] =
                    fast_sigmoid(gl) * fast_tanh(gr);
            }
        }
    }
}

// ---------------------------------------------------------------------------
// v19 agg GEMM, MX-FP8 with FRAGMENT PING-PONG pipeline: 128x128, BK=128,
// 4 waves (64x64), 2 blocks/CU, LDS 64KB dbuf.
// Per phase t: issue tile t+1's 16 ds_reads into pong set (buf (t+1)%2);
// lgkmcnt(15) drains tile t's 16 reads (+<=1 new; gfx9 lgkmcnt field max=15);
// BAR (all waves' reads of buf t%2 done -> restage safe); STAGE tile t+2 ->
// buf t%2; MFMA tile t from ping set (tile t+1 reads complete on LDS pipe in
// background); vmcnt(0); BAR (publish).
// Regs: acc 64 + fa/fb[2] 128 + addr ~= 230 <= 256 cap at (256,2).
// ---------------------------------------------------------------------------
#define SCB() __builtin_amdgcn_sched_barrier(0)
#define BARR() do { SCB(); __builtin_amdgcn_s_barrier(); SCB(); } while (0)
#define WAITK15 do { SCB(); asm volatile("s_waitcnt lgkmcnt(15)" ::: "memory"); SCB(); } while (0)
#define WAITK0  do { SCB(); asm volatile("s_waitcnt lgkmcnt(0)"  ::: "memory"); SCB(); } while (0)
#define GATEZ do { SCB(); asm volatile("s_waitcnt vmcnt(0)" ::: "memory"); SCB(); } while (0)

template <int STAGE>
__global__ __launch_bounds__(256, 2) void agg_mx(
    const u8* __restrict__ A, const u8* __restrict__ Bt,
    const u16* __restrict__ Wt, const float* __restrict__ fcb,
    u8* __restrict__ P, int win0, int vbase, int nout, int ks, float ysc) {
    const int tid = threadIdx.x, lane = tid & 63, wid = tid >> 6;   // 0..3
    const int wr = wid >> 1, wc = wid & 1;
    const int bx = blockIdx.x, by = blockIdx.y, z = blockIdx.z;
    const int rowBase = by * 128, colBase = bx * 128;
    const int win = win0 + z;
    __shared__ u8 ldsb[65536];
    __shared__ float biasSm[128];
    biasSm[tid & 127] = fcb[(win * 3 + ks) * 128 + (tid & 127)];
    const u8* Az = (STAGE == 0) ? (A + (size_t)win * 1024)
                                : (A + (size_t)z * 2048 * 4096);
    const size_t strideA = (STAGE == 0) ? 12288 : 4096;

    const int r8 = lane >> 3;
    const int c16 = (lane & 7) * 16;
    auto stageA = [&](int buf, int s, int kt) {
        kt &= 31;
        int r_l = s * 32 + wid * 8;
        GLL(Az + (size_t)(rowBase + r_l + r8) * strideA + (size_t)kt * 128 + c16,
            &ldsb[buf * 32768 + r_l * 128]);
    };
    auto stageB = [&](int buf, int s, int kt) {
        kt &= 31;
        int r_l = s * 32 + wid * 8;
        GLL(Bt + (size_t)(vbase + colBase + r_l + r8) * 4096 + (size_t)kt * 128 + c16,
            &ldsb[buf * 32768 + 16384 + r_l * 128]);
    };
#define STAGE8M(buf, kt) do { stageA(buf, 0, kt); stageA(buf, 1, kt); \
                              stageA(buf, 2, kt); stageA(buf, 3, kt); \
                              stageB(buf, 0, kt); stageB(buf, 1, kt); \
                              stageB(buf, 2, kt); stageB(buf, 3, kt); } while (0)

    f32x4 acc[4][4] = {};
    i32x8 fa[2][4], fb[2][4];
    const int q0 = lane >> 4;

#define RD_SET(S, BUF)                                                        \
    _Pragma("unroll") for (int mm = 0; mm < 4; mm++) {                        \
        int r = wr * 64 + mm * 16 + (lane & 15);                              \
        int h = r & 7;                                                        \
        const u8* bp = &ldsb[(BUF) * 32768 + r * 128];                        \
        ((uint4*)&fa[S][mm])[0] = *(const uint4*)&bp[((2 * q0) ^ h) * 16];    \
        ((uint4*)&fa[S][mm])[1] = *(const uint4*)&bp[((2 * q0 + 1) ^ h) * 16];\
    }                                                                         \
    _Pragma("unroll") for (int nn = 0; nn < 4; nn++) {                        \
        int r = wc * 64 + nn * 16 + (lane & 15);                              \
        int h = r & 7;                                                        \
        const u8* bp = &ldsb[(BUF) * 32768 + 16384 + r * 128];                \
        ((uint4*)&fb[S][nn])[0] = *(const uint4*)&bp[((2 * q0) ^ h) * 16];    \
        ((uint4*)&fb[S][nn])[1] = *(const uint4*)&bp[((2 * q0 + 1) ^ h) * 16];\
    }
#define MFMA_SET(S)                                                           \
    __builtin_amdgcn_s_setprio(1);                                            \
    _Pragma("unroll") for (int mm = 0; mm < 4; mm++)                          \
    _Pragma("unroll") for (int nn = 0; nn < 4; nn++)                          \
        acc[mm][nn] = __builtin_amdgcn_mfma_scale_f32_16x16x128_f8f6f4(       \
            fa[S][mm], fb[S][nn], acc[mm][nn], 0, 0, 0, 127, 0, 127);         \
    __builtin_amdgcn_s_setprio(0);

// phase T (T%2 == CUR): read tile T+1 frags -> set NXT; drain reads(T);
// barrier; restage buf CUR with tile T+2; MFMA tile T; drain stage; barrier.
#define PHASE(CUR, NXT, T) do {                                               \
    RD_SET(NXT, NXT);                                                         \
    WAITK15;                                                                  \
    BARR();                                                                   \
    STAGE8M(CUR, (T) + 2);                                                    \
    SCB();                                                                    \
    MFMA_SET(CUR);                                                            \
    GATEZ;                                                                    \
    BARR();                                                                   \
} while (0)

    // prologue: tiles 0,1 -> bufs 0,1; full drain; read tile 0 frags
    STAGE8M(0, 0);
    STAGE8M(1, 1);
    GATEZ;
    BARR();
    RD_SET(0, 0);

    for (int i = 0; i < 15; i++) {
        PHASE(0, 1, 2 * i);
        PHASE(1, 0, 2 * i + 1);
    }
    PHASE(0, 1, 30);   // reads tile-31 frags; stages wrap (tile 0, harmless)
    // tail: tile 31
    WAITK0;
    MFMA_SET(1);

    // ================= fused GLU epilogue (bf16) =================
    __syncthreads();   // all GLLs drained (phase-30 GATEZ) + reads waited
    u16* YT = (u16*)ldsb;   // [2 bat][128 v][64 c] bf16, 16B-chunk swz
#pragma unroll
    for (int mm = 0; mm < 4; mm++) {
        int c0 = mm * 16 + q0 * 4;
#pragma unroll
        for (int nn = 0; nn < 4; nn++) {
            int v = wc * 64 + nn * 16 + (lane & 15);
            ushort4 pk;
            pk.x = f2b(acc[mm][nn][0] * ysc); pk.y = f2b(acc[mm][nn][1] * ysc);
            pk.z = f2b(acc[mm][nn][2] * ysc); pk.w = f2b(acc[mm][nn][3] * ysc);
            int addr = (wr * 128 + v) * 64 + (((c0 >> 3) ^ (v & 7)) << 3) + (c0 & 7);
            *(ushort4*)&YT[addr] = pk;
        }
    }
    __syncthreads();

    const int bat = wid >> 1, fh = wid & 1;
    const u16* Wl = Wt + (size_t)(win * 3 + ks) * 8192;
    u8* Pz = P + (size_t)z * 2048 * nout;
    bf16x8 aw[4][2];
#pragma unroll
    for (int p = 0; p < 4; p++) {
        int mt = (p & 1) + fh * 2 + (p >> 1) * 4;
#pragma unroll
        for (int kk = 0; kk < 2; kk++)
            aw[p][kk] = *(const bf16x8*)&Wl[(mt * 16 + (lane & 15)) * 64 + kk * 32 + q0 * 8];
    }
#pragma unroll
    for (int vp = 0; vp < 4; vp++) {
        f32x4 acc2[4][2] = {};
        bf16x8 bq2[2][2];
#pragma unroll
        for (int nt = 0; nt < 2; nt++) {
            int v = vp * 32 + nt * 16 + (lane & 15);
#pragma unroll
            for (int kk = 0; kk < 2; kk++) {
                int ch = kk * 4 + q0;
                bq2[nt][kk] = *(const bf16x8*)&YT[(bat * 128 + v) * 64 + ((ch ^ (v & 7)) << 3)];
            }
        }
#pragma unroll
        for (int p = 0; p < 4; p++)
#pragma unroll
            for (int nt = 0; nt < 2; nt++)
#pragma unroll
                for (int kk = 0; kk < 2; kk++)
                    acc2[p][nt] = __builtin_amdgcn_mfma_f32_16x16x32_bf16(
                        aw[p][kk], bq2[nt][kk], acc2[p][nt], 0, 0, 0);
#pragma unroll
        for (int p = 0; p < 2; p++) {
            int mt = (p & 1) + fh * 2;
#pragma unroll
            for (int j = 0; j < 4; j++) {
                int f = mt * 16 + q0 * 4 + j;
                float b1 = biasSm[f], b2v = biasSm[f + 64];
                int row = rowBase + bat * 64 + f;
#pragma unroll
                for (int nt = 0; nt < 2; nt++) {
                    float g1 = acc2[p][nt][j] + b1;
                    float g2 = acc2[p + 2][nt][j] + b2v;
                    float val = g1 * fast_sigmoid(g2);
                    int colg = colBase + vp * 32 + nt * 16 + (lane & 15);
                    int seg = colg & ~127;
                    int chunk = (((colg >> 4) & 7) ^ (row & 7));
                    Pz[(size_t)row * nout + seg + chunk * 16 + (colg & 15)] =
                        f2e4m3(val * 512.0f);
                }
            }
        }
    }
#undef RD_SET
#undef MFMA_SET
#undef PHASE
#undef STAGE8M
}

// ---------------------------------------------------------------------------
// final: out[b,win,n,f] += max(P1mid, P2mid, P3) ; P* fp8 swz128 (x512)
// ---------------------------------------------------------------------------
__device__ __forceinline__ uint4 ld_swz(const u8* p, size_t rowBytes, size_t k, int h) {
    size_t seg = k & ~(size_t)127;
    int chunk = ((int)(k >> 4) & 7) ^ h;
    return *(const uint4*)&p[rowBytes + seg + chunk * 16];
}

__global__ void final_add(const u8* __restrict__ P1, const u8* __restrict__ P2,
                          const u8* __restrict__ P3, float* __restrict__ out, int win0) {
    const int n0 = blockIdx.x * 64, b = blockIdx.y, z = blockIdx.z;
    const int win = win0 + z;
    const int tid = threadIdx.x;
    __shared__ float tl[64][65];
    {
        int f = tid >> 2, q = tid & 3;
        int row = b * 64 + f;
        int h = row & 7;
        size_t rb12 = ((size_t)z * 2048 + row) * 4096;
        size_t rb3  = ((size_t)z * 2048 + row) * 1024;
        uint4 a  = ld_swz(P1, rb12, (size_t)1024 + n0 + q * 16, h);
        uint4 c2 = ld_swz(P2, rb12, (size_t)1024 + n0 + q * 16, h);
        uint4 d  = ld_swz(P3, rb3, (size_t)n0 + q * 16, h);
        const u32 aw[4] = {a.x, a.y, a.z, a.w};
        const u32 bw[4] = {c2.x, c2.y, c2.z, c2.w};
        const u32 dw[4] = {d.x, d.y, d.z, d.w};
#pragma unroll
        for (int w = 0; w < 4; w++)
#pragma unroll
            for (int j = 0; j < 4; j++) {
                float va = e4m3f((aw[w] >> (j * 8)) & 0xffu);
                float vb = e4m3f((bw[w] >> (j * 8)) & 0xffu);
                float vd = e4m3f((dw[w] >> (j * 8)) & 0xffu);
                tl[q * 16 + w * 4 + j][f] = fmaxf(fmaxf(va, vb), vd) * (1.0f / 512.0f);
            }
    }
    __syncthreads();
    {
        int n = tid >> 2, q = tid & 3;
        size_t oo = ((size_t)(b * 9 + win) * 1024 + n0 + n) * 64 + q * 16;
#pragma unroll
        for (int i = 0; i < 16; i += 4) {
            float4 cur = *(const float4*)&out[oo + i];
            cur.x += tl[n][q * 16 + i + 0];
            cur.y += tl[n][q * 16 + i + 1];
            cur.z += tl[n][q * 16 + i + 2];
            cur.w += tl[n][q * 16 + i + 3];
            *(float4*)&out[oo + i] = cur;
        }
    }
}

// ---------------------------------------------------------------------------
extern "C" void kernel_launch(void* const* d_in, const int* in_sizes, int n_in,
                              void* d_out, int out_size, void* d_ws, size_t ws_size,
                              hipStream_t stream) {
    const float* data = (const float*)d_in[0];
    const float* adj  = (const float*)d_in[1];
    const float* temb = (const float*)d_in[2];
    const float* semb = (const float*)d_in[3];
    const float* cwl  = (const float*)d_in[4];
    const float* cbl  = (const float*)d_in[5];
    const float* cwr  = (const float*)d_in[6];
    const float* cbr  = (const float*)d_in[7];
    const float* fcw  = (const float*)d_in[8];
    const float* fcb  = (const float*)d_in[9];
    float* out = (float*)d_out;

    const float YS1 = 1.0f / 8192.0f;
    const float YS2 = 1.0f / 4194304.0f;

    char* p = (char*)d_ws;
    auto alloc = [&](size_t bytes) -> char* {
        char* r = p;
        p += (bytes + 255) & ~(size_t)255;
        return r;
    };
    const size_t SZ_XT  = 2048UL * 12288;
    const size_t SZ_XN  = 32UL * 12 * 1024 * 64 * 2;
    const size_t SZ_ADJ = 4096UL * 4096;
    const size_t SZ_WT  = 27UL * 128 * 64 * 2;
    const size_t SZ_WC  = 128UL * 128 * 2;
    const size_t SZ_P12 = 2048UL * 4096;
    const size_t SZ_P3  = 2048UL * 1024;
    u8*  XT   = (u8*)alloc(SZ_XT);
    u8*  adjb = (u8*)alloc(SZ_ADJ);
    u16* Wt   = (u16*)alloc(SZ_WT);
    u16* Wc   = (u16*)alloc(SZ_WC);
    size_t fixed = (size_t)(p - (char*)d_ws);

    bool single = (fixed + 9 * (2 * SZ_P12) + SZ_XN + 1024 <= ws_size);
    if (single) {
        u8* P1 = (u8*)alloc(9 * SZ_P12);
        u8* P2 = (u8*)alloc(9 * SZ_P12);
        u8* P3 = XT;
        u16* Xn = (u16*)P2;

        cvt_adj_fp8<<<4096, 256, 0, stream>>>(adj, adjb, 4096 * 4096);
        prep_x<<<dim3(16, 12, 32), 256, 0, stream>>>(data, temb, semb, Xn, XT);
        prep_w<<<28, 256, 0, stream>>>(fcw, cwl, cwr, Wt, Wc);
        dconv_gemm<<<dim3(8, 9, 32), 256, 0, stream>>>(Xn, Wc, cbl, cbr, out);

        agg_mx<0><<<dim3(32, 16, 9), 256, 0, stream>>>(XT, adjb, Wt, fcb, P1, 0, 0, 4096, 0, YS1);
        agg_mx<1><<<dim3(32, 16, 9), 256, 0, stream>>>(P1, adjb, Wt, fcb, P2, 0, 0, 4096, 1, YS2);
        agg_mx<1><<<dim3(8, 16, 9), 256, 0, stream>>>(P2, adjb, Wt, fcb, P3, 0, 1024, 1024, 2, YS2);
        final_add<<<dim3(16, 32, 9), 256, 0, stream>>>(P1, P2, P3, out, 0);
    } else {
        char* winBase = p;
        size_t avail = ws_size - (size_t)(winBase - (char*)d_ws);
        const size_t perwin = 2 * SZ_P12 + SZ_P3 + 3 * 256;
        int cap = (int)(avail / perwin);
        if (cap > 9) cap = 9;
        if (cap < 1) cap = 1;
        u8* P1 = (u8*)alloc((size_t)cap * SZ_P12);
        u8* P2 = (u8*)alloc((size_t)cap * SZ_P12);
        u8* P3 = (u8*)alloc((size_t)cap * SZ_P3);
        u16* Xn = ((size_t)cap * perwin >= SZ_XN + 256) ? (u16*)winBase : (u16*)alloc(SZ_XN);

        cvt_adj_fp8<<<4096, 256, 0, stream>>>(adj, adjb, 4096 * 4096);
        prep_x<<<dim3(16, 12, 32), 256, 0, stream>>>(data, temb, semb, Xn, XT);
        prep_w<<<28, 256, 0, stream>>>(fcw, cwl, cwr, Wt, Wc);
        dconv_gemm<<<dim3(8, 9, 32), 256, 0, stream>>>(Xn, Wc, cbl, cbr, out);

        int ngroups = (9 + cap - 1) / cap;
        int gbase = 9 / ngroups, grem = 9 % ngroups;
        int w0 = 0;
        for (int g = 0; g < ngroups; g++) {
            int cw = gbase + (g < grem ? 1 : 0);
            agg_mx<0><<<dim3(32, 16, cw), 256, 0, stream>>>(XT, adjb, Wt, fcb, P1, w0, 0, 4096, 0, YS1);
            agg_mx<1><<<dim3(32, 16, cw), 256, 0, stream>>>(P1, adjb, Wt, fcb, P2, w0, 0, 4096, 1, YS2);
            agg_mx<1><<<dim3(8, 16, cw), 256, 0, stream>>>(P2, adjb, Wt, fcb, P3, w0, 1024, 1024, 2, YS2);
            final_add<<<dim3(16, 32, cw), 256, 0, stream>>>(P1, P2, P3, out, w0);
            w0 += cw;
        }
    }
}

// Round 20
// 1012.068 us; speedup vs baseline: 1.0508x; 1.0508x over previous
//
#include <hip/hip_runtime.h>
#include <math.h>

typedef unsigned char  u8;
typedef unsigned short u16;
typedef unsigned int   u32;
typedef __attribute__((ext_vector_type(8))) short bf16x8;
typedef __attribute__((ext_vector_type(8))) int   i32x8;
typedef __attribute__((ext_vector_type(4))) float f32x4;

typedef const void __attribute__((address_space(1))) gv1_t;
typedef void       __attribute__((address_space(3))) lv3_t;
#define GLL(g, l) __builtin_amdgcn_global_load_lds((gv1_t*)(g), (lv3_t*)(l), 16, 0, 0)

__device__ __forceinline__ u16 f2b(float x) {
    union { float f; u32 u; } v; v.f = x;
    u32 r = v.u + 0x7FFFu + ((v.u >> 16) & 1u);
    return (u16)(r >> 16);
}
__device__ __forceinline__ float b2f(u32 x) {
    union { u32 u; float f; } v; v.u = x << 16;
    return v.f;
}
__device__ __forceinline__ float fast_sigmoid(float x) {
    return __builtin_amdgcn_rcpf(1.0f + __builtin_amdgcn_exp2f(-x * 1.44269504f));
}
__device__ __forceinline__ float fast_tanh(float x) {
    return 2.0f * __builtin_amdgcn_rcpf(1.0f + __builtin_amdgcn_exp2f(-x * 2.88539008f)) - 1.0f;
}

// f32 -> OCP e4m3fn (RNE-ish, clamp 448, subnormals via *512 round)
__device__ __forceinline__ u8 f2e4m3(float x) {
    union { float f; u32 u; } v; v.f = x;
    u32 s = (v.u >> 24) & 0x80u;
    u32 a = v.u & 0x7fffffffu;
    if (a >= 0x43d80000u) return (u8)(s | 0x7e);
    if (a >= 0x3c800000u) {
        u32 expf = a >> 23;
        u32 keep = (a >> 20) & 7u;
        u32 rest = a & 0xfffffu;
        u32 vv = ((expf - 120u) << 3) | keep;
        vv += (rest > 0x80000u) || ((rest == 0x80000u) && (keep & 1u));
        return (u8)(s | vv);
    }
    float t = fabsf(x) * 512.0f;
    u32 ti = (u32)(t + 0.5f);
    return (u8)(s | ti);
}
__device__ __forceinline__ float e4m3f(u32 b) {
    u32 e = (b >> 3) & 15u, m = b & 7u;
    union { u32 u; float f; } t;
    t.u = ((e + 120u) << 23) | (m << 20);
    float v = e ? t.f : ((float)m * 0.001953125f);
    return (b & 0x80u) ? -v : v;
}

// ===========================================================================
// SWZ128 storage for fp8 GEMM operands: within each 128B-aligned row segment,
// 16B chunk c stored at phys c ^ (row&7). GLL staging is a pure linear copy;
// fragment reads apply the XOR.
// ===========================================================================

// prep: adj f32 -> fp8 (x8192), swz128 store
__global__ void cvt_adj_fp8(const float* __restrict__ a, u8* __restrict__ o, int n) {
    for (int i = (blockIdx.x * 256 + threadIdx.x) * 4; i < n; i += gridDim.x * 256 * 4) {
        float4 v = *(const float4*)&a[i];
        u32 pk = (u32)f2e4m3(v.x * 8192.0f) | ((u32)f2e4m3(v.y * 8192.0f) << 8)
               | ((u32)f2e4m3(v.z * 8192.0f) << 16) | ((u32)f2e4m3(v.w * 8192.0f) << 24);
        int row = i >> 12;                       // 4096 B per row
        int addr = (i & ~127) | (((((i >> 4) & 7) ^ (row & 7)) << 4)) | (i & 15);
        *(u32*)&o[addr] = pk;
    }
}

// prep: x = data + temb + semb; Xn bf16 [b][t][n][c]; XT fp8 swz128
__global__ void prep_x(const float* __restrict__ data, const float* __restrict__ temb,
                       const float* __restrict__ semb, u16* __restrict__ Xn, u8* __restrict__ XT) {
    const int n0 = blockIdx.x * 64, t = blockIdx.y, b = blockIdx.z;
    const int tid = threadIdx.x;
    __shared__ u16 lt[64][66];
#pragma unroll
    for (int p = 0; p < 4; p++) {
        int n = p * 16 + (tid >> 4);
        int c = (tid & 15) * 4;
        size_t gi = ((size_t)(b * 12 + t) * 1024 + n0 + n) * 64 + c;
        float4 v  = *(const float4*)&data[gi];
        float4 tv = *(const float4*)&temb[t * 64 + c];
        float4 sv = *(const float4*)&semb[(n0 + n) * 64 + c];
        u16 u0 = f2b(v.x + tv.x + sv.x);
        u16 u1 = f2b(v.y + tv.y + sv.y);
        u16 u2 = f2b(v.z + tv.z + sv.z);
        u16 u3 = f2b(v.w + tv.w + sv.w);
        uint2 pk; pk.x = (u32)u0 | ((u32)u1 << 16); pk.y = (u32)u2 | ((u32)u3 << 16);
        *(uint2*)&Xn[gi] = pk;
        lt[n][c + 0] = u0; lt[n][c + 1] = u1; lt[n][c + 2] = u2; lt[n][c + 3] = u3;
    }
    __syncthreads();
    const int c = tid >> 2, q = tid & 3;
    u32 w[4];
#pragma unroll
    for (int i = 0; i < 4; i++) {
        u32 b0 = f2e4m3(b2f(lt[q * 16 + i * 4 + 0][c]));
        u32 b1 = f2e4m3(b2f(lt[q * 16 + i * 4 + 1][c]));
        u32 b2 = f2e4m3(b2f(lt[q * 16 + i * 4 + 2][c]));
        u32 b3 = f2e4m3(b2f(lt[q * 16 + i * 4 + 3][c]));
        w[i] = b0 | (b1 << 8) | (b2 << 16) | (b3 << 24);
    }
    const int row = b * 64 + c;
    size_t kk = (size_t)t * 1024 + n0 + q * 16;
    size_t seg = kk & ~(size_t)127;
    int chunk = (((int)(kk >> 4) & 7) ^ (row & 7));
    uint4 pk; pk.x = w[0]; pk.y = w[1]; pk.z = w[2]; pk.w = w[3];
    *(uint4*)&XT[(size_t)row * 12288 + seg + chunk * 16] = pk;
}

// prep: fc_w -> Wt [27][128][64] bf16 ; conv weights -> Wc [128][128] bf16
__global__ void prep_w(const float* __restrict__ fcw, const float* __restrict__ cwl,
                       const float* __restrict__ cwr, u16* __restrict__ Wt, u16* __restrict__ Wc) {
    const int blk = blockIdx.x, tid = threadIdx.x;
    if (blk < 27) {
        const float* src = fcw + (size_t)blk * 64 * 128;
        u16* dst = Wt + (size_t)blk * 128 * 64;
        for (int e = tid; e < 8192; e += 256) {
            int c = e >> 7, f = e & 127;
            dst[f * 64 + c] = f2b(src[c * 128 + f]);
        }
    } else {
        for (int e = tid; e < 16384; e += 256) {
            int o = e >> 7, k = e & 127;
            float v = (o < 64) ? cwl[(o * 64 + (k & 63)) * 2 + (k >> 6)]
                               : cwr[((o - 64) * 64 + (k & 63)) * 2 + (k >> 6)];
            Wc[o * 128 + k] = f2b(v);
        }
    }
}

// ---------------------------------------------------------------------------
// gated dilated conv as GEMM (bf16, unchanged)
// ---------------------------------------------------------------------------
__global__ __launch_bounds__(256) void dconv_gemm(
    const u16* __restrict__ Xn, const u16* __restrict__ Wc,
    const float* __restrict__ cbl, const float* __restrict__ cbr,
    float* __restrict__ out) {
    const int n0 = blockIdx.x * 128, t = blockIdx.y, b = blockIdx.z;
    const int tid = threadIdx.x, lane = tid & 63, wid = tid >> 6;
    __shared__ u16 alds[2][128 * 32];
    const u16* base0 = Xn + (size_t)(b * 12 + t) * 1024 * 64;
    const u16* base3 = Xn + (size_t)(b * 12 + t + 3) * 1024 * 64;

    auto stage = [&](int buf, int kt) {
        int k0 = kt * 32;
#pragma unroll
        for (int q = 0; q < 2; q++) {
            int r = wid * 32 + q * 16 + (lane >> 2);
            int k = k0 + (lane & 3) * 8;
            const u16* gs = (k < 64) ? base0 + (size_t)(n0 + r) * 64 + k
                                     : base3 + (size_t)(n0 + r) * 64 + (k - 64);
            GLL(gs, &alds[buf][(wid * 32 + q * 16) * 32]);
        }
    };

    f32x4 acc[2][8] = {};
    stage(0, 0);
    __syncthreads();
    const int a_off = (wid * 32 + (lane & 15)) * 32 + (lane >> 4) * 8;
    for (int kt = 0; kt < 4; kt++) {
        int cur = kt & 1;
        if (kt < 3) stage(cur ^ 1, kt + 1);
        bf16x8 af[2];
#pragma unroll
        for (int m = 0; m < 2; m++) af[m] = *(const bf16x8*)&alds[cur][a_off + m * 16 * 32];
#pragma unroll
        for (int n = 0; n < 8; n++) {
            bf16x8 bq = *(const bf16x8*)&Wc[(n * 16 + (lane & 15)) * 128 + kt * 32 + (lane >> 4) * 8];
#pragma unroll
            for (int m = 0; m < 2; m++)
                acc[m][n] = __builtin_amdgcn_mfma_f32_16x16x32_bf16(af[m], bq, acc[m][n], 0, 0, 0);
        }
        __syncthreads();
    }
#pragma unroll
    for (int m = 0; m < 2; m++) {
#pragma unroll
        for (int n = 0; n < 4; n++) {
            int fp = n * 16 + (lane & 15);
            float b1 = cbl[fp], b2 = cbr[fp];
#pragma unroll
            for (int j = 0; j < 4; j++) {
                int row = wid * 32 + m * 16 + (lane >> 4) * 4 + j;
                float gl = acc[m][n][j] + b1;
                float gr = acc[m][n + 4][j] + b2;
                out[((size_t)(b * 9 + t) * 1024 + n0 + row) * 64 + fp] =
                    fast_sigmoid(gl) * fast_tanh(gr);
            }
        }
    }
}

// ---------------------------------------------------------------------------
// r14 agg GEMM (best measured, restored verbatim): MX-FP8 128x128, BK=128,
// 4 waves (64x64), 2 blocks/CU, LDS-staged A+B, v7 2-barrier schedule.
// Per tile: BAR; 16 ds_read_b128; lgkm(0); BAR; 8 GLL (tile t+2 -> read buf,
// linear copy of swz128 storage); 16 mfma_scale; vmcnt(8).
// ---------------------------------------------------------------------------
#define SCB() __builtin_amdgcn_sched_barrier(0)
#define BARR() do { SCB(); __builtin_amdgcn_s_barrier(); SCB(); } while (0)
#define WAITK0 do { asm volatile("s_waitcnt lgkmcnt(0)" ::: "memory"); SCB(); } while (0)
#define GATE8 do { SCB(); asm volatile("s_waitcnt vmcnt(8)" ::: "memory"); SCB(); } while (0)
#define GATEZ do { SCB(); asm volatile("s_waitcnt vmcnt(0)" ::: "memory"); SCB(); } while (0)

template <int STAGE>
__global__ __launch_bounds__(256, 2) void agg_mx(
    const u8* __restrict__ A, const u8* __restrict__ Bt,
    const u16* __restrict__ Wt, const float* __restrict__ fcb,
    u8* __restrict__ P, int win0, int vbase, int nout, int ks, float ysc) {
    const int tid = threadIdx.x, lane = tid & 63, wid = tid >> 6;   // 0..3
    const int wr = wid >> 1, wc = wid & 1;
    const int bx = blockIdx.x, by = blockIdx.y, z = blockIdx.z;
    const int rowBase = by * 128, colBase = bx * 128;
    const int win = win0 + z;
    __shared__ u8 ldsb[65536];
    __shared__ float biasSm[128];
    biasSm[tid & 127] = fcb[(win * 3 + ks) * 128 + (tid & 127)];
    const u8* Az = (STAGE == 0) ? (A + (size_t)win * 1024)
                                : (A + (size_t)z * 2048 * 4096);
    const size_t strideA = (STAGE == 0) ? 12288 : 4096;

    const int r8 = lane >> 3;
    const int c16 = (lane & 7) * 16;
    auto stageA = [&](int buf, int s, int kt) {
        int r_l = s * 32 + wid * 8;
        GLL(Az + (size_t)(rowBase + r_l + r8) * strideA + (size_t)kt * 128 + c16,
            &ldsb[buf * 32768 + r_l * 128]);
    };
    auto stageB = [&](int buf, int s, int kt) {
        int r_l = s * 32 + wid * 8;
        GLL(Bt + (size_t)(vbase + colBase + r_l + r8) * 4096 + (size_t)kt * 128 + c16,
            &ldsb[buf * 32768 + 16384 + r_l * 128]);
    };
#define STAGE8M(buf, kt) do { stageA(buf, 0, kt); stageA(buf, 1, kt); \
                              stageA(buf, 2, kt); stageA(buf, 3, kt); \
                              stageB(buf, 0, kt); stageB(buf, 1, kt); \
                              stageB(buf, 2, kt); stageB(buf, 3, kt); } while (0)

    f32x4 acc[4][4] = {};
    i32x8 fa[4], fb[4];
    const int q0 = lane >> 4;

#define RD_ABM(buf)                                                           \
    _Pragma("unroll") for (int mm = 0; mm < 4; mm++) {                        \
        int r = wr * 64 + mm * 16 + (lane & 15);                              \
        int h = r & 7;                                                        \
        const u8* bp = &ldsb[(buf) * 32768 + r * 128];                        \
        ((uint4*)&fa[mm])[0] = *(const uint4*)&bp[((2 * q0) ^ h) * 16];       \
        ((uint4*)&fa[mm])[1] = *(const uint4*)&bp[((2 * q0 + 1) ^ h) * 16];   \
    }                                                                         \
    _Pragma("unroll") for (int nn = 0; nn < 4; nn++) {                        \
        int r = wc * 64 + nn * 16 + (lane & 15);                              \
        int h = r & 7;                                                        \
        const u8* bp = &ldsb[(buf) * 32768 + 16384 + r * 128];                \
        ((uint4*)&fb[nn])[0] = *(const uint4*)&bp[((2 * q0) ^ h) * 16];       \
        ((uint4*)&fb[nn])[1] = *(const uint4*)&bp[((2 * q0 + 1) ^ h) * 16];   \
    }
#define MFMA16M()                                                             \
    __builtin_amdgcn_s_setprio(1);                                            \
    _Pragma("unroll") for (int mm = 0; mm < 4; mm++)                          \
    _Pragma("unroll") for (int nn = 0; nn < 4; nn++)                          \
        acc[mm][nn] = __builtin_amdgcn_mfma_scale_f32_16x16x128_f8f6f4(       \
            fa[mm], fb[nn], acc[mm][nn], 0, 0, 0, 127, 0, 127);               \
    __builtin_amdgcn_s_setprio(0);

#define TILE14M(RB, T2S) do {                                                 \
    BARR();                                                                   \
    RD_ABM(RB);                                                               \
    WAITK0;                                                                   \
    BARR();                                                                   \
    STAGE8M(RB, T2S);                                                         \
    SCB();                                                                    \
    MFMA16M();                                                                \
    GATE8;                                                                    \
} while (0)

    STAGE8M(0, 0);
    STAGE8M(1, 1);
    GATE8;

    for (int t = 0; t < 30; t += 2) {
        TILE14M(0, t + 2);
        TILE14M(1, t + 3);
    }
    BARR();
    RD_ABM(0);
    WAITK0;
    BARR();
    MFMA16M();
    GATEZ;
    BARR();
    RD_ABM(1);
    WAITK0;
    MFMA16M();

    // ================= fused GLU epilogue (bf16) =================
    __syncthreads();
    u16* YT = (u16*)ldsb;   // [2 bat][128 v][64 c] bf16, 16B-chunk swz
#pragma unroll
    for (int mm = 0; mm < 4; mm++) {
        int c0 = mm * 16 + q0 * 4;
#pragma unroll
        for (int nn = 0; nn < 4; nn++) {
            int v = wc * 64 + nn * 16 + (lane & 15);
            ushort4 pk;
            pk.x = f2b(acc[mm][nn][0] * ysc); pk.y = f2b(acc[mm][nn][1] * ysc);
            pk.z = f2b(acc[mm][nn][2] * ysc); pk.w = f2b(acc[mm][nn][3] * ysc);
            int addr = (wr * 128 + v) * 64 + (((c0 >> 3) ^ (v & 7)) << 3) + (c0 & 7);
            *(ushort4*)&YT[addr] = pk;
        }
    }
    __syncthreads();

    const int bat = wid >> 1, fh = wid & 1;
    const u16* Wl = Wt + (size_t)(win * 3 + ks) * 8192;
    u8* Pz = P + (size_t)z * 2048 * nout;
    bf16x8 aw[4][2];
#pragma unroll
    for (int p = 0; p < 4; p++) {
        int mt = (p & 1) + fh * 2 + (p >> 1) * 4;
#pragma unroll
        for (int kk = 0; kk < 2; kk++)
            aw[p][kk] = *(const bf16x8*)&Wl[(mt * 16 + (lane & 15)) * 64 + kk * 32 + q0 * 8];
    }
#pragma unroll
    for (int vp = 0; vp < 4; vp++) {
        f32x4 acc2[4][2] = {};
        bf16x8 bq2[2][2];
#pragma unroll
        for (int nt = 0; nt < 2; nt++) {
            int v = vp * 32 + nt * 16 + (lane & 15);
#pragma unroll
            for (int kk = 0; kk < 2; kk++) {
                int ch = kk * 4 + q0;
                bq2[nt][kk] = *(const bf16x8*)&YT[(bat * 128 + v) * 64 + ((ch ^ (v & 7)) << 3)];
            }
        }
#pragma unroll
        for (int p = 0; p < 4; p++)
#pragma unroll
            for (int nt = 0; nt < 2; nt++)
#pragma unroll
                for (int kk = 0; kk < 2; kk++)
                    acc2[p][nt] = __builtin_amdgcn_mfma_f32_16x16x32_bf16(
                        aw[p][kk], bq2[nt][kk], acc2[p][nt], 0, 0, 0);
#pragma unroll
        for (int p = 0; p < 2; p++) {
            int mt = (p & 1) + fh * 2;
#pragma unroll
            for (int j = 0; j < 4; j++) {
                int f = mt * 16 + q0 * 4 + j;
                float b1 = biasSm[f], b2v = biasSm[f + 64];
                int row = rowBase + bat * 64 + f;
#pragma unroll
                for (int nt = 0; nt < 2; nt++) {
                    float g1 = acc2[p][nt][j] + b1;
                    float g2 = acc2[p + 2][nt][j] + b2v;
                    float val = g1 * fast_sigmoid(g2);
                    int colg = colBase + vp * 32 + nt * 16 + (lane & 15);
                    int seg = colg & ~127;
                    int chunk = (((colg >> 4) & 7) ^ (row & 7));
                    Pz[(size_t)row * nout + seg + chunk * 16 + (colg & 15)] =
                        f2e4m3(val * 512.0f);
                }
            }
        }
    }
#undef RD_ABM
#undef MFMA16M
#undef TILE14M
#undef STAGE8M
}

// ---------------------------------------------------------------------------
// final: out[b,win,n,f] += max(P1mid, P2mid, P3) ; P* fp8 swz128 (x512)
// ---------------------------------------------------------------------------
__device__ __forceinline__ uint4 ld_swz(const u8* p, size_t rowBytes, size_t k, int h) {
    size_t seg = k & ~(size_t)127;
    int chunk = ((int)(k >> 4) & 7) ^ h;
    return *(const uint4*)&p[rowBytes + seg + chunk * 16];
}

__global__ void final_add(const u8* __restrict__ P1, const u8* __restrict__ P2,
                          const u8* __restrict__ P3, float* __restrict__ out, int win0) {
    const int n0 = blockIdx.x * 64, b = blockIdx.y, z = blockIdx.z;
    const int win = win0 + z;
    const int tid = threadIdx.x;
    __shared__ float tl[64][65];
    {
        int f = tid >> 2, q = tid & 3;
        int row = b * 64 + f;
        int h = row & 7;
        size_t rb12 = ((size_t)z * 2048 + row) * 4096;
        size_t rb3  = ((size_t)z * 2048 + row) * 1024;
        uint4 a  = ld_swz(P1, rb12, (size_t)1024 + n0 + q * 16, h);
        uint4 c2 = ld_swz(P2, rb12, (size_t)1024 + n0 + q * 16, h);
        uint4 d  = ld_swz(P3, rb3, (size_t)n0 + q * 16, h);
        const u32 aw[4] = {a.x, a.y, a.z, a.w};
        const u32 bw[4] = {c2.x, c2.y, c2.z, c2.w};
        const u32 dw[4] = {d.x, d.y, d.z, d.w};
#pragma unroll
        for (int w = 0; w < 4; w++)
#pragma unroll
            for (int j = 0; j < 4; j++) {
                float va = e4m3f((aw[w] >> (j * 8)) & 0xffu);
                float vb = e4m3f((bw[w] >> (j * 8)) & 0xffu);
                float vd = e4m3f((dw[w] >> (j * 8)) & 0xffu);
                tl[q * 16 + w * 4 + j][f] = fmaxf(fmaxf(va, vb), vd) * (1.0f / 512.0f);
            }
    }
    __syncthreads();
    {
        int n = tid >> 2, q = tid & 3;
        size_t oo = ((size_t)(b * 9 + win) * 1024 + n0 + n) * 64 + q * 16;
#pragma unroll
        for (int i = 0; i < 16; i += 4) {
            float4 cur = *(const float4*)&out[oo + i];
            cur.x += tl[n][q * 16 + i + 0];
            cur.y += tl[n][q * 16 + i + 1];
            cur.z += tl[n][q * 16 + i + 2];
            cur.w += tl[n][q * 16 + i + 3];
            *(float4*)&out[oo + i] = cur;
        }
    }
}

// ---------------------------------------------------------------------------
extern "C" void kernel_launch(void* const* d_in, const int* in_sizes, int n_in,
                              void* d_out, int out_size, void* d_ws, size_t ws_size,
                              hipStream_t stream) {
    const float* data = (const float*)d_in[0];
    const float* adj  = (const float*)d_in[1];
    const float* temb = (const float*)d_in[2];
    const float* semb = (const float*)d_in[3];
    const float* cwl  = (const float*)d_in[4];
    const float* cbl  = (const float*)d_in[5];
    const float* cwr  = (const float*)d_in[6];
    const float* cbr  = (const float*)d_in[7];
    const float* fcw  = (const float*)d_in[8];
    const float* fcb  = (const float*)d_in[9];
    float* out = (float*)d_out;

    const float YS1 = 1.0f / 8192.0f;
    const float YS2 = 1.0f / 4194304.0f;

    char* p = (char*)d_ws;
    auto alloc = [&](size_t bytes) -> char* {
        char* r = p;
        p += (bytes + 255) & ~(size_t)255;
        return r;
    };
    const size_t SZ_XT  = 2048UL * 12288;
    const size_t SZ_XN  = 32UL * 12 * 1024 * 64 * 2;
    const size_t SZ_ADJ = 4096UL * 4096;
    const size_t SZ_WT  = 27UL * 128 * 64 * 2;
    const size_t SZ_WC  = 128UL * 128 * 2;
    const size_t SZ_P12 = 2048UL * 4096;
    const size_t SZ_P3  = 2048UL * 1024;
    u8*  XT   = (u8*)alloc(SZ_XT);
    u8*  adjb = (u8*)alloc(SZ_ADJ);
    u16* Wt   = (u16*)alloc(SZ_WT);
    u16* Wc   = (u16*)alloc(SZ_WC);
    size_t fixed = (size_t)(p - (char*)d_ws);

    bool single = (fixed + 9 * (2 * SZ_P12) + SZ_XN + 1024 <= ws_size);
    if (single) {
        u8* P1 = (u8*)alloc(9 * SZ_P12);
        u8* P2 = (u8*)alloc(9 * SZ_P12);
        u8* P3 = XT;
        u16* Xn = (u16*)P2;

        cvt_adj_fp8<<<4096, 256, 0, stream>>>(adj, adjb, 4096 * 4096);
        prep_x<<<dim3(16, 12, 32), 256, 0, stream>>>(data, temb, semb, Xn, XT);
        prep_w<<<28, 256, 0, stream>>>(fcw, cwl, cwr, Wt, Wc);
        dconv_gemm<<<dim3(8, 9, 32), 256, 0, stream>>>(Xn, Wc, cbl, cbr, out);

        agg_mx<0><<<dim3(32, 16, 9), 256, 0, stream>>>(XT, adjb, Wt, fcb, P1, 0, 0, 4096, 0, YS1);
        agg_mx<1><<<dim3(32, 16, 9), 256, 0, stream>>>(P1, adjb, Wt, fcb, P2, 0, 0, 4096, 1, YS2);
        agg_mx<1><<<dim3(8, 16, 9), 256, 0, stream>>>(P2, adjb, Wt, fcb, P3, 0, 1024, 1024, 2, YS2);
        final_add<<<dim3(16, 32, 9), 256, 0, stream>>>(P1, P2, P3, out, 0);
    } else {
        char* winBase = p;
        size_t avail = ws_size - (size_t)(winBase - (char*)d_ws);
        const size_t perwin = 2 * SZ_P12 + SZ_P3 + 3 * 256;
        int cap = (int)(avail / perwin);
        if (cap > 9) cap = 9;
        if (cap < 1) cap = 1;
        u8* P1 = (u8*)alloc((size_t)cap * SZ_P12);
        u8* P2 = (u8*)alloc((size_t)cap * SZ_P12);
        u8* P3 = (u8*)alloc((size_t)cap * SZ_P3);
        u16* Xn = ((size_t)cap * perwin >= SZ_XN + 256) ? (u16*)winBase : (u16*)alloc(SZ_XN);

        cvt_adj_fp8<<<4096, 256, 0, stream>>>(adj, adjb, 4096 * 4096);
        prep_x<<<dim3(16, 12, 32), 256, 0, stream>>>(data, temb, semb, Xn, XT);
        prep_w<<<28, 256, 0, stream>>>(fcw, cwl, cwr, Wt, Wc);
        dconv_gemm<<<dim3(8, 9, 32), 256, 0, stream>>>(Xn, Wc, cbl, cbr, out);

        int ngroups = (9 + cap - 1) / cap;
        int gbase = 9 / ngroups, grem = 9 % ngroups;
        int w0 = 0;
        for (int g = 0; g < ngroups; g++) {
            int cw = gbase + (g < grem ? 1 : 0);
            agg_mx<0><<<dim3(32, 16, cw), 256, 0, stream>>>(XT, adjb, Wt, fcb, P1, w0, 0, 4096, 0, YS1);
            agg_mx<1><<<dim3(32, 16, cw), 256, 0, stream>>>(P1, adjb, Wt, fcb, P2, w0, 0, 4096, 1, YS2);
            agg_mx<1><<<dim3(8, 16, cw), 256, 0, stream>>>(P2, adjb, Wt, fcb, P3, w0, 1024, 1024, 2, YS2);
            final_add<<<dim3(16, 32, cw), 256, 0, stream>>>(P1, P2, P3, out, w0);
            w0 += cw;
        }
    }
}